// Round 2
// baseline (539.084 us; speedup 1.0000x reference)
//
#include <hip/hip_runtime.h>
#include <hip/hip_fp16.h>
#include <cstddef>
#include <cstdint>

#define DIM 128
#define SEQ 2048
#define NB 32
#define NCH 512
#define NROWS (NB * SEQ)          // 65536

// ws layout: cmb fp16 [NROWS][NCH], then WfT fp32 [512][128]
#define CMB_BYTES ((size_t)NROWS * NCH * 2)     // 67,108,864
#define WFT_OFF   CMB_BYTES
#define WFT_BYTES ((size_t)512 * 128 * 4)       // 262,144
#define WS_NEEDED (WFT_OFF + WFT_BYTES)         // ~64.3 MiB

__device__ __forceinline__ float sigf(float v) {
    return 1.0f / (1.0f + __expf(-v));
}

// ---------------------------------------------------------------------------
// k0: WfT[f][d] = Wf[d][f]   (Wf is [128 d][512 f] row-major)
// ---------------------------------------------------------------------------
__global__ void k0_wft(const float* __restrict__ Wf, float* __restrict__ WfT) {
    int idx = blockIdx.x * 256 + threadIdx.x;   // 65536 total
    int f = idx >> 7, d = idx & 127;
    WfT[idx] = Wf[d * NCH + f];
}

// ---------------------------------------------------------------------------
// kfused: per block (b, cg): 64 channels, full S=2048 in 32 tiles of 64.
//   proj GEMM [64 s x 128 d] @ [128 d x 128 j] -> gate -> sequential scan
//   -> cmb fp16.   j = cc*2 + proj(0=pa,1=pi), channel c = cg*64+cc.
// ---------------------------------------------------------------------------
__global__ __launch_bounds__(256) void kfused(
        const float* __restrict__ x,
        const float* __restrict__ Wa_u, const float* __restrict__ ba_u,
        const float* __restrict__ Wi_u, const float* __restrict__ bi_u,
        const float* __restrict__ g_u,
        const float* __restrict__ Wa_w, const float* __restrict__ ba_w,
        const float* __restrict__ Wi_w, const float* __restrict__ bi_w,
        const float* __restrict__ g_w,
        __half* __restrict__ cmb) {
    __shared__ float  Ws[128][132];    // [d][j]
    __shared__ float  xs[64][132];     // [s_local][d]
    __shared__ float2 au2[64][65];     // [s_local][cc] = (a,u); .x := h after scan

    const int tid = threadIdx.x;
    const int b  = blockIdx.x;         // 0..31
    const int cg = blockIdx.y;         // 0..7
    const int p  = cg >> 2;            // 0 = unweighted, 1 = weighted
    const int ebase = (cg & 3) * 64;

    const float* Wa  = p ? Wa_w : Wa_u;
    const float* Wi  = p ? Wi_w : Wi_u;
    const float* bap = p ? ba_w : ba_u;
    const float* bip = p ? bi_w : bi_u;
    const float* gp  = p ? g_w  : g_u;

    // stage projection weights: Ws[d][j] = (j odd ? Wi : Wa)[ebase + j/2][d]
    for (int idx = tid; idx < 128 * 128; idx += 256) {
        int j = idx >> 7, d = idx & 127;
        const float* row = ((j & 1) ? Wi : Wa) + (size_t)(ebase + (j >> 1)) * DIM;
        Ws[d][j] = row[d];
    }

    const int tx = tid & 15, ty = tid >> 4;

    // per-thread channel params: [h][q], cc = h*32 + 2*tx + q
    float rba[2][2], rbi[2][2], ral[2][2];
#pragma unroll
    for (int h = 0; h < 2; ++h)
#pragma unroll
        for (int q = 0; q < 2; ++q) {
            int e = ebase + h * 32 + 2 * tx + q;
            rba[h][q] = bap[e];
            rbi[h][q] = bip[e];
            ral[h][q] = sigf(gp[e]);
        }

    float hreg = 0.0f;                               // scan state (wave 0 only)
    const float* xrow = x + (size_t)b * SEQ * DIM;
    __half* cmbb = cmb + (size_t)b * SEQ * NCH + cg * 64;

    __syncthreads();                                 // Ws ready

    for (int t = 0; t < 32; ++t) {
        const int s0 = t * 64;

        // ---- stage x tile: 64 s x 128 d ----
#pragma unroll
        for (int it = 0; it < 8; ++it) {
            int flat = it * 256 + tid;               // 2048 float4s
            int r = flat >> 5, d4 = flat & 31;
            float4 v = *(const float4*)(xrow + (size_t)(s0 + r) * DIM + d4 * 4);
            *(float4*)&xs[r][d4 * 4] = v;
        }
        __syncthreads();

        // ---- GEMM: acc[i][h*4+jj] = proj(s = s0+4ty+i, j = h*64+4tx+jj) ----
        float acc[4][8];
#pragma unroll
        for (int i = 0; i < 4; ++i)
#pragma unroll
            for (int j = 0; j < 8; ++j) acc[i][j] = 0.0f;

        for (int k = 0; k < 128; k += 4) {
            float4 av[4], bv0[4], bv1[4];
#pragma unroll
            for (int i = 0; i < 4; ++i)
                av[i] = *(const float4*)&xs[4 * ty + i][k];
#pragma unroll
            for (int q = 0; q < 4; ++q) {
                bv0[q] = *(const float4*)&Ws[k + q][4 * tx];
                bv1[q] = *(const float4*)&Ws[k + q][64 + 4 * tx];
            }
#pragma unroll
            for (int i = 0; i < 4; ++i) {
                const float* ap = (const float*)&av[i];
#pragma unroll
                for (int q = 0; q < 4; ++q) {
                    float a = ap[q];
                    const float* b0 = (const float*)&bv0[q];
                    const float* b1 = (const float*)&bv1[q];
                    acc[i][0] = fmaf(a, b0[0], acc[i][0]);
                    acc[i][1] = fmaf(a, b0[1], acc[i][1]);
                    acc[i][2] = fmaf(a, b0[2], acc[i][2]);
                    acc[i][3] = fmaf(a, b0[3], acc[i][3]);
                    acc[i][4] = fmaf(a, b1[0], acc[i][4]);
                    acc[i][5] = fmaf(a, b1[1], acc[i][5]);
                    acc[i][6] = fmaf(a, b1[2], acc[i][6]);
                    acc[i][7] = fmaf(a, b1[3], acc[i][7]);
                }
            }
        }

        // ---- gate epilogue -> au2 ----
#pragma unroll
        for (int i = 0; i < 4; ++i) {
            int sl = 4 * ty + i;
            int sg = s0 + sl;
            float sc = p ? __expf((float)sg * (3.0f / 2047.0f)) : 1.0f;
#pragma unroll
            for (int h = 0; h < 2; ++h)
#pragma unroll
                for (int q = 0; q < 2; ++q) {
                    float par = acc[i][h * 4 + 2 * q];
                    float pir = acc[i][h * 4 + 2 * q + 1];
                    float pa = fmaf(par, sc, rba[h][q]);
                    float pi = fmaf(pir, sc, rbi[h][q]);
                    float rst = sigf(pa);
                    float ig  = sigf(pi);
                    float a   = ral[h][q] * exp2f(-rst * 1.5849625007211562f); // 3^-rst
                    float u   = sqrtf(fmaxf(1.0f - a * a, 0.0f)) * ig * pi;
                    au2[sl][h * 32 + 2 * tx + q] = make_float2(a, u);
                }
        }
        __syncthreads();

        // ---- sequential scan: wave 0, thread tid owns channel cc = tid ----
        if (tid < 64) {
            float hh = hreg;
#pragma unroll 8
            for (int s = 0; s < 64; ++s) {
                float2 v = au2[s][tid];
                hh = fmaf(v.x, hh, v.y);
                au2[s][tid].x = hh;
            }
            hreg = hh;
        }
        __syncthreads();

        // ---- write cmb fp16 ----
        for (int idx = tid; idx < 4096; idx += 256) {
            int r = idx >> 6, cc = idx & 63;
            cmbb[(size_t)(s0 + r) * NCH + cc] = __float2half(au2[r][cc].x);
        }
        // next-iter au2 writes are gated by the post-stage barrier; no sync needed
    }
}

// ---------------------------------------------------------------------------
// k3: out[65536,128] = cmb(fp16)[65536,512] @ WfT[512,128] + bf
//     128x128 tile, 256 threads, 8x8 per thread as 2x2 groups of 4x4
// ---------------------------------------------------------------------------
__global__ __launch_bounds__(256) void k3_out(
        const __half* __restrict__ cmb, const float* __restrict__ WfT,
        const float* __restrict__ bfv, float* __restrict__ out) {
    __shared__ float As[128][36];
    __shared__ float Bs[32][132];

    const int tid = threadIdx.x;
    const int tx = tid & 15, ty = tid >> 4;
    const int row0 = blockIdx.x * 128;

    float acc[2][2][4][4];
#pragma unroll
    for (int a0 = 0; a0 < 2; ++a0)
#pragma unroll
        for (int b0 = 0; b0 < 2; ++b0)
#pragma unroll
            for (int i = 0; i < 4; ++i)
#pragma unroll
                for (int j = 0; j < 4; ++j) acc[a0][b0][i][j] = 0.0f;

    for (int kc = 0; kc < NCH; kc += 32) {
        // stage A: 128 rows x 32 k (fp16 -> fp32)
#pragma unroll
        for (int it = 0; it < 2; ++it) {
            int flat = it * 256 + tid;           // 512 loads of 8 halfs
            int r = flat >> 2, k8 = flat & 3;
            uint4 v = *(const uint4*)(cmb + (size_t)(row0 + r) * NCH + kc + k8 * 8);
            const __half2* hp = (const __half2*)&v;
            float2 f0 = __half22float2(hp[0]);
            float2 f1 = __half22float2(hp[1]);
            float2 f2 = __half22float2(hp[2]);
            float2 f3 = __half22float2(hp[3]);
            float* dst = &As[r][k8 * 8];
            dst[0] = f0.x; dst[1] = f0.y; dst[2] = f1.x; dst[3] = f1.y;
            dst[4] = f2.x; dst[5] = f2.y; dst[6] = f3.x; dst[7] = f3.y;
        }
        // stage B: 32 k x 128 d
#pragma unroll
        for (int it = 0; it < 4; ++it) {
            int flat = it * 256 + tid;
            int ki = flat >> 5, j4 = flat & 31;
            float4 v = *(const float4*)(WfT + (size_t)(kc + ki) * DIM + j4 * 4);
            *(float4*)&Bs[ki][j4 * 4] = v;
        }
        __syncthreads();

#pragma unroll
        for (int k = 0; k < 32; k += 4) {
            float4 af[2][4];
            float4 bfr[4][2];
#pragma unroll
            for (int rg = 0; rg < 2; ++rg)
#pragma unroll
                for (int i = 0; i < 4; ++i)
                    af[rg][i] = *(const float4*)&As[rg * 64 + 4 * ty + i][k];
#pragma unroll
            for (int j = 0; j < 4; ++j)
#pragma unroll
                for (int cgp = 0; cgp < 2; ++cgp)
                    bfr[j][cgp] = *(const float4*)&Bs[k + j][cgp * 64 + 4 * tx];
#pragma unroll
            for (int rg = 0; rg < 2; ++rg)
#pragma unroll
                for (int i = 0; i < 4; ++i) {
                    const float* ap = (const float*)&af[rg][i];
#pragma unroll
                    for (int j = 0; j < 4; ++j) {
                        float av = ap[j];
#pragma unroll
                        for (int cgp = 0; cgp < 2; ++cgp) {
                            const float* bp = (const float*)&bfr[j][cgp];
#pragma unroll
                            for (int jj = 0; jj < 4; ++jj)
                                acc[rg][cgp][i][jj] = fmaf(av, bp[jj], acc[rg][cgp][i][jj]);
                        }
                    }
                }
        }
        __syncthreads();
    }

    float4 b0 = *(const float4*)&bfv[4 * tx];
    float4 b1 = *(const float4*)&bfv[64 + 4 * tx];
#pragma unroll
    for (int rg = 0; rg < 2; ++rg)
#pragma unroll
        for (int i = 0; i < 4; ++i) {
            int grow = row0 + rg * 64 + 4 * ty + i;
            float4 o0, o1;
            o0.x = acc[rg][0][i][0] + b0.x;
            o0.y = acc[rg][0][i][1] + b0.y;
            o0.z = acc[rg][0][i][2] + b0.z;
            o0.w = acc[rg][0][i][3] + b0.w;
            o1.x = acc[rg][1][i][0] + b1.x;
            o1.y = acc[rg][1][i][1] + b1.y;
            o1.z = acc[rg][1][i][2] + b1.z;
            o1.w = acc[rg][1][i][3] + b1.w;
            *(float4*)&out[(size_t)grow * DIM + 4 * tx] = o0;
            *(float4*)&out[(size_t)grow * DIM + 64 + 4 * tx] = o1;
        }
}

// ---------------------------------------------------------------------------
extern "C" void kernel_launch(void* const* d_in, const int* in_sizes, int n_in,
                              void* d_out, int out_size, void* d_ws, size_t ws_size,
                              hipStream_t stream) {
    if (ws_size < WS_NEEDED) return;   // needs only ~64.3 MiB now

    const float* x    = (const float*)d_in[0];
    const float* Wa_u = (const float*)d_in[1];
    const float* ba_u = (const float*)d_in[2];
    const float* Wi_u = (const float*)d_in[3];
    const float* bi_u = (const float*)d_in[4];
    const float* g_u  = (const float*)d_in[5];
    const float* Wa_w = (const float*)d_in[6];
    const float* ba_w = (const float*)d_in[7];
    const float* Wi_w = (const float*)d_in[8];
    const float* bi_w = (const float*)d_in[9];
    const float* g_w  = (const float*)d_in[10];
    const float* Wf   = (const float*)d_in[11];
    const float* bfv  = (const float*)d_in[12];
    float* out = (float*)d_out;

    char* ws = (char*)d_ws;
    __half* cmb = (__half*)ws;
    float*  WfT = (float*)(ws + WFT_OFF);

    hipLaunchKernelGGL(k0_wft, dim3(256), dim3(256), 0, stream, Wf, WfT);
    hipLaunchKernelGGL(kfused, dim3(32, 8), dim3(256), 0, stream,
                       x, Wa_u, ba_u, Wi_u, bi_u, g_u,
                       Wa_w, ba_w, Wi_w, bi_w, g_w, cmb);
    hipLaunchKernelGGL(k3_out, dim3(512), dim3(256), 0, stream,
                       cmb, WfT, bfv, out);
}

// Round 3
// 479.952 us; speedup vs baseline: 1.1232x; 1.1232x over previous
//
#include <hip/hip_runtime.h>
#include <hip/hip_fp16.h>
#include <cstddef>
#include <cstdint>

#define DIM 128
#define SEQ 2048
#define NB 32
#define NCH 512
#define NROWS (NB * SEQ)          // 65536

typedef _Float16 half8 __attribute__((ext_vector_type(8)));
typedef float    f32x4 __attribute__((ext_vector_type(4)));

// ws layout: cmb fp16 [NROWS][NCH], then Wfg fp16 fragment-linear [512*128]
#define CMB_BYTES ((size_t)NROWS * NCH * 2)       // 67,108,864
#define WFG_OFF   CMB_BYTES
#define WFG_BYTES ((size_t)NCH * DIM * 2)         // 131,072
#define WS_NEEDED (WFG_OFF + WFG_BYTES)           // < round-2's 67,371,008 (proven available)

__device__ __forceinline__ float sigf(float v) {
    return 1.0f / (1.0f + __expf(-v));
}

// ---------------------------------------------------------------------------
// k0: build Wfg = Wf quantized to fp16, pre-swizzled into MFMA B-fragment
//     linear layout. Page = (kb, ks, ct), slot = lane = q*16+n16, 8 halfs (j).
//     Element: B[k][n] = Wf[n*512 + k], k = kb*64 + ks*32 + q*8 + j, n = ct*16+n16.
// ---------------------------------------------------------------------------
__global__ void k0_wfg(const float* __restrict__ Wf, _Float16* __restrict__ Wfg) {
    int o = blockIdx.x * 256 + threadIdx.x;     // 65536 total
    int j    = o & 7;
    int lane = (o >> 3) & 63;
    int q    = lane >> 4, n16 = lane & 15;
    int ct   = (o >> 9) & 7;
    int ks   = (o >> 12) & 1;
    int kb   = o >> 13;
    int k = kb * 64 + ks * 32 + q * 8 + j;
    int n = ct * 16 + n16;
    Wfg[o] = (_Float16)Wf[n * NCH + k];
}

// ---------------------------------------------------------------------------
// kfused: block = (batch b, channel-group cg of 32 channels).
//   s-loop: 32 tiles of 64 steps. Per tile: fp32 GEMM [64s x 128d]@[128d x 64j]
//   (thread = 8 contiguous s x 1 channel), gates, register-resident blocked
//   scan (8-step affine compose per thread -> wave0 scans 8 segments -> replay),
//   fp16 store to cmb. Carry crosses tiles in LDS (exact, per-channel).
//   LDS ~69 KB -> 2 blocks/CU.
// ---------------------------------------------------------------------------
__global__ __launch_bounds__(256, 2) void kfused(
        const float* __restrict__ x,
        const float* __restrict__ Wa_u, const float* __restrict__ ba_u,
        const float* __restrict__ Wi_u, const float* __restrict__ bi_u,
        const float* __restrict__ g_u,
        const float* __restrict__ Wa_w, const float* __restrict__ ba_w,
        const float* __restrict__ Wi_w, const float* __restrict__ bi_w,
        const float* __restrict__ g_w,
        _Float16* __restrict__ cmb) {
    __shared__ float  Ws[128][64];    // [d][j], unpadded (broadcast-friendly reads)
    __shared__ float  xs[64][128];    // [s_local][d], unpadded
    __shared__ float2 seg[8][33];     // per-(ty, ch) segment (A, U)
    __shared__ float  pref[8][33];    // per-(ty, ch) incoming h
    __shared__ float  carry[32];      // per-channel h across tiles

    const int tid = threadIdx.x;
    const int b  = blockIdx.x;        // 0..31
    const int cg = blockIdx.y;        // 0..15 ; global channels cg*32..+31
    const int p  = cg >> 3;           // path: 0 unweighted, 1 weighted
    const int ebase = (cg & 7) * 32;  // channel base within path

    const float* Wa  = p ? Wa_w : Wa_u;
    const float* Wi  = p ? Wi_w : Wi_u;
    const float* bap = p ? ba_w : ba_u;
    const float* bip = p ? bi_w : bi_u;
    const float* gp  = p ? g_w  : g_u;

    // stage Ws[d][j]: j = 2*el + proj -> (proj? Wi:Wa)[ebase+el][d]
    for (int idx = tid; idx < 128 * 64; idx += 256) {
        int j = idx & 63, d = idx >> 6;
        const float* W = (j & 1) ? Wi : Wa;
        Ws[d][j] = W[(size_t)(ebase + (j >> 1)) * DIM + d];
    }
    if (tid < 32) carry[tid] = 0.0f;

    const int tx = tid & 31;          // channel within group
    const int ty = tid >> 5;          // s-segment 0..7 (8 steps each)

    const int e = ebase + tx;
    const float rba = bap[e];
    const float rbi = bip[e];
    const float ral = sigf(gp[e]);

    const float* xrow = x + (size_t)b * SEQ * DIM;
    _Float16* cmbb = cmb + (size_t)b * SEQ * NCH + cg * 32 + tx;

    __syncthreads();

    for (int t = 0; t < 32; ++t) {
        const int s0 = t * 64;

        // ---- stage x tile (coalesced f4, conflict-free LDS writes) ----
#pragma unroll
        for (int i = 0; i < 8; ++i) {
            int f = tid + i * 256;                 // 2048 float4s
            int r = f >> 5, c4 = f & 31;
            float4 v = *(const float4*)(xrow + (size_t)(s0 + r) * DIM + c4 * 4);
            *(float4*)&xs[r][c4 * 4] = v;
        }
        __syncthreads();

        // ---- GEMM: rows ty*8..+7, cols j = 2*tx (pa), 2*tx+1 (pi) ----
        float acc0[8], acc1[8];
#pragma unroll
        for (int i = 0; i < 8; ++i) { acc0[i] = 0.0f; acc1[i] = 0.0f; }

        for (int k = 0; k < 128; k += 4) {
            float4 af[8];
            float2 bv[4];
#pragma unroll
            for (int i = 0; i < 8; ++i)
                af[i] = *(const float4*)&xs[ty * 8 + i][k];
#pragma unroll
            for (int q = 0; q < 4; ++q)
                bv[q] = *(const float2*)&Ws[k + q][tx * 2];
#pragma unroll
            for (int q = 0; q < 4; ++q) {
#pragma unroll
                for (int i = 0; i < 8; ++i) {
                    float av = ((const float*)&af[i])[q];
                    acc0[i] = fmaf(av, bv[q].x, acc0[i]);
                    acc1[i] = fmaf(av, bv[q].y, acc1[i]);
                }
            }
        }

        // ---- gates + per-thread 8-step affine compose ----
        float a_s[8], u_s[8];
        float Aseg = 1.0f, Useg = 0.0f;
#pragma unroll
        for (int i = 0; i < 8; ++i) {
            int sg = s0 + ty * 8 + i;
            float sc = p ? __expf((float)sg * (3.0f / 2047.0f)) : 1.0f;
            float pa = fmaf(acc0[i], sc, rba);
            float pi = fmaf(acc1[i], sc, rbi);
            float rst = sigf(pa);
            float ig  = sigf(pi);
            float a   = ral * exp2f(-rst * 1.5849625007211562f);   // alpha * 3^-rst
            float u   = sqrtf(fmaxf(1.0f - a * a, 0.0f)) * ig * pi;
            a_s[i] = a; u_s[i] = u;
            Aseg *= a;
            Useg = fmaf(a, Useg, u);
        }
        seg[ty][tx] = make_float2(Aseg, Useg);
        __syncthreads();

        // ---- inter-segment scan: lane tx owns channel, 8 segments ----
        if (tid < 32) {
            float H = carry[tid];
#pragma unroll
            for (int ts = 0; ts < 8; ++ts) {
                float2 AU = seg[ts][tid];
                pref[ts][tid] = H;
                H = fmaf(AU.x, H, AU.y);
            }
            carry[tid] = H;
        }
        __syncthreads();

        // ---- replay with incoming h, store fp16 ----
        float h = pref[ty][tx];
        _Float16* dst = cmbb + (size_t)(s0 + ty * 8) * NCH;
#pragma unroll
        for (int i = 0; i < 8; ++i) {
            h = fmaf(a_s[i], h, u_s[i]);
            dst[(size_t)i * NCH] = (_Float16)h;
        }
        // next-iter xs staging is safe: all GEMM reads happened before the
        // seg barrier, which every thread has passed.
    }
}

// ---------------------------------------------------------------------------
// k3: out[65536,128] = cmb(fp16) @ Wf^T(fp16) + bf  via mfma_f32_16x16x32_f16.
//   Block 256 thr / 4 waves, tile 128 rows x 128 cols, K = 512 in 8 chunks of 64.
//   LDS holds A and B in fragment-linear pages (lane-linear b128, conflict-free).
// ---------------------------------------------------------------------------
__global__ __launch_bounds__(256, 2) void k3_mfma(
        const _Float16* __restrict__ cmb, const _Float16* __restrict__ Wfg,
        const float* __restrict__ bfv, float* __restrict__ out) {
    __shared__ _Float16 As[16 * 512];   // 16 pages (rt 0..7, ks 0..1) x 512 halfs
    __shared__ _Float16 Bs[16 * 512];   // 16 pages (ks 0..1, ct 0..7) x 512 halfs

    const int tid  = threadIdx.x;
    const int lane = tid & 63;
    const int w    = tid >> 6;          // wave 0..3, rows w*32..+31
    const int row0 = blockIdx.x * 128;
    const int q    = lane >> 4;         // quad
    const int nn   = lane & 15;

    f32x4 acc[2][8];
#pragma unroll
    for (int rt = 0; rt < 2; ++rt)
#pragma unroll
        for (int ct = 0; ct < 8; ++ct)
            acc[rt][ct] = (f32x4){0.0f, 0.0f, 0.0f, 0.0f};

    for (int kb = 0; kb < 8; ++kb) {
        const int kc = kb * 64;
        // stage A: 1024 granules of 8 halfs; coalesced global, frag-linear LDS
#pragma unroll
        for (int i = 0; i < 4; ++i) {
            int f = tid + i * 256;
            int r = f >> 3, k8 = f & 7;
            uint4 v = *(const uint4*)(cmb + (size_t)(row0 + r) * NCH + kc + k8 * 8);
            int rt = r >> 4, m = r & 15, ks = k8 >> 2, qq = k8 & 3;
            *(uint4*)&As[(((rt * 2 + ks) * 64) + qq * 16 + m) * 8] = v;
        }
        // stage B: already fragment-linear in global; straight copy
#pragma unroll
        for (int i = 0; i < 4; ++i) {
            int f = tid + i * 256;
            uint4 v = *(const uint4*)(Wfg + (size_t)kb * 8192 + (size_t)f * 8);
            *(uint4*)&Bs[(size_t)f * 8] = v;
        }
        __syncthreads();

#pragma unroll
        for (int ks = 0; ks < 2; ++ks) {
            half8 a0 = *(const half8*)&As[(((w * 2 + 0) * 2 + ks) * 512) + lane * 8];
            half8 a1 = *(const half8*)&As[(((w * 2 + 1) * 2 + ks) * 512) + lane * 8];
#pragma unroll
            for (int ct = 0; ct < 8; ++ct) {
                half8 bb = *(const half8*)&Bs[((ks * 8 + ct) * 512) + lane * 8];
                acc[0][ct] = __builtin_amdgcn_mfma_f32_16x16x32_f16(a0, bb, acc[0][ct], 0, 0, 0);
                acc[1][ct] = __builtin_amdgcn_mfma_f32_16x16x32_f16(a1, bb, acc[1][ct], 0, 0, 0);
            }
        }
        __syncthreads();
    }

    // epilogue: C/D layout col = lane&15, row = quad*4 + reg  [m89-verified]
#pragma unroll
    for (int rt = 0; rt < 2; ++rt) {
        int rbase = row0 + w * 32 + rt * 16 + q * 4;
#pragma unroll
        for (int ct = 0; ct < 8; ++ct) {
            int col = ct * 16 + nn;
            float bias = bfv[col];
#pragma unroll
            for (int reg = 0; reg < 4; ++reg)
                out[(size_t)(rbase + reg) * DIM + col] = acc[rt][ct][reg] + bias;
        }
    }
}

// ---------------------------------------------------------------------------
extern "C" void kernel_launch(void* const* d_in, const int* in_sizes, int n_in,
                              void* d_out, int out_size, void* d_ws, size_t ws_size,
                              hipStream_t stream) {
    if (ws_size < WS_NEEDED) return;

    const float* x    = (const float*)d_in[0];
    const float* Wa_u = (const float*)d_in[1];
    const float* ba_u = (const float*)d_in[2];
    const float* Wi_u = (const float*)d_in[3];
    const float* bi_u = (const float*)d_in[4];
    const float* g_u  = (const float*)d_in[5];
    const float* Wa_w = (const float*)d_in[6];
    const float* ba_w = (const float*)d_in[7];
    const float* Wi_w = (const float*)d_in[8];
    const float* bi_w = (const float*)d_in[9];
    const float* g_w  = (const float*)d_in[10];
    const float* Wf   = (const float*)d_in[11];
    const float* bfv  = (const float*)d_in[12];
    float* out = (float*)d_out;

    char* ws = (char*)d_ws;
    _Float16* cmb = (_Float16*)ws;
    _Float16* Wfg = (_Float16*)(ws + WFG_OFF);

    hipLaunchKernelGGL(k0_wfg, dim3(256), dim3(256), 0, stream, Wf, Wfg);
    hipLaunchKernelGGL(kfused, dim3(32, 16), dim3(256), 0, stream,
                       x, Wa_u, ba_u, Wi_u, bi_u, g_u,
                       Wa_w, ba_w, Wi_w, bi_w, g_w, cmb);
    hipLaunchKernelGGL(k3_mfma, dim3(512), dim3(256), 0, stream,
                       cmb, Wfg, bfv, out);
}

// Round 4
// 219.180 us; speedup vs baseline: 2.4596x; 2.1898x over previous
//
#include <hip/hip_runtime.h>
#include <hip/hip_fp16.h>
#include <cstddef>
#include <cstdint>

#define DIM 128
#define SEQ 2048
#define NB 32
#define NCH 512
#define NROWS (NB * SEQ)          // 65536

typedef _Float16 half8 __attribute__((ext_vector_type(8)));
typedef float    f32x4 __attribute__((ext_vector_type(4)));

// ws layout: cmb fp16 [NROWS][NCH], then Wfg fp16 fragment-linear [512*128]
#define CMB_BYTES ((size_t)NROWS * NCH * 2)       // 67,108,864
#define WFG_OFF   CMB_BYTES
#define WFG_BYTES ((size_t)NCH * DIM * 2)         // 131,072
#define WS_NEEDED (WFG_OFF + WFG_BYTES)

__device__ __forceinline__ float sigf(float v) {
    return 1.0f / (1.0f + __expf(-v));
}

// ---------------------------------------------------------------------------
// k0: Wfg = Wf (fp16) pre-swizzled into MFMA B-fragment linear layout.
// ---------------------------------------------------------------------------
__global__ void k0_wfg(const float* __restrict__ Wf, _Float16* __restrict__ Wfg) {
    int o = blockIdx.x * 256 + threadIdx.x;     // 65536 total
    int j    = o & 7;
    int lane = (o >> 3) & 63;
    int q    = lane >> 4, n16 = lane & 15;
    int ct   = (o >> 9) & 7;
    int ks   = (o >> 12) & 1;
    int kb   = o >> 13;
    int k = kb * 64 + ks * 32 + q * 8 + j;
    int n = ct * 16 + n16;
    Wfg[o] = (_Float16)Wf[n * NCH + k];
}

// ---------------------------------------------------------------------------
// kfused v3: block = (batch b, 32-channel group). s-tiles of 64.
//   Projection via mfma_f32_16x16x32_f16: A = x-tile fp16 (LDS), B = weights
//   fp16 register-resident (16 frags). Gate epilogue in C-layout (4 contiguous
//   s per thread), register segment-compose -> 16-seg LDS serial scan ->
//   replay -> coalesced fp16 cmb store via LDS bounce.
// ---------------------------------------------------------------------------
__global__ __launch_bounds__(256, 2) void kfused(
        const float* __restrict__ x,
        const float* __restrict__ Wa_u, const float* __restrict__ ba_u,
        const float* __restrict__ Wi_u, const float* __restrict__ bi_u,
        const float* __restrict__ g_u,
        const float* __restrict__ Wa_w, const float* __restrict__ ba_w,
        const float* __restrict__ Wi_w, const float* __restrict__ bi_w,
        const float* __restrict__ g_w,
        _Float16* __restrict__ cmb) {
    __shared__ _Float16 xs[64][136];     // [s][d] fp16, pad 8 (16B-aligned rows)
    __shared__ float2   seg[16][33];     // (A,U) per (segment, channel)
    __shared__ float    pref[16][33];    // incoming h per (segment, channel)
    __shared__ float    carry[32];       // per-channel h across tiles
    __shared__ _Float16 hbuf[64][40];    // [s][cc] bounce for coalesced store

    const int tid  = threadIdx.x;
    const int lane = tid & 63;
    const int w    = tid >> 6;           // wave: rows w*16..+15 of the s-tile
    const int quad = lane >> 4;
    const int n16  = lane & 15;

    const int b  = blockIdx.x;           // 0..31
    const int cg = blockIdx.y;           // 0..15
    const int p  = cg >> 3;              // path
    const int ebase = (cg & 7) * 32;

    const float* Wa  = p ? Wa_w : Wa_u;
    const float* Wi  = p ? Wi_w : Wi_u;
    const float* bap = p ? ba_w : ba_u;
    const float* bip = p ? bi_w : bi_u;
    const float* gp  = p ? g_w  : g_u;

    // ---- B-fragments, register-resident: bf[ks][nt]
    //  nt 0,1 = pa (cc 0..15 / 16..31); nt 2,3 = pi.
    //  B[k = ks*32+quad*8+j][n] = Wsel[e = ebase + (nt&1)*16 + n16][k]
    half8 bf[4][4];
#pragma unroll
    for (int ks = 0; ks < 4; ++ks)
#pragma unroll
        for (int nt = 0; nt < 4; ++nt) {
            int e = ebase + (nt & 1) * 16 + n16;
            const float* Wp = (nt >> 1) ? Wi : Wa;
            const float* src = Wp + (size_t)e * DIM + ks * 32 + quad * 8;
            float4 v0 = *(const float4*)src;
            float4 v1 = *(const float4*)(src + 4);
            half8 hv;
            hv[0] = (_Float16)v0.x; hv[1] = (_Float16)v0.y;
            hv[2] = (_Float16)v0.z; hv[3] = (_Float16)v0.w;
            hv[4] = (_Float16)v1.x; hv[5] = (_Float16)v1.y;
            hv[6] = (_Float16)v1.z; hv[7] = (_Float16)v1.w;
            bf[ks][nt] = hv;
        }

    // per-thread channel params (hh = 0/1 -> cc = hh*16 + n16)
    float rba[2], rbi[2], ral[2];
#pragma unroll
    for (int hh = 0; hh < 2; ++hh) {
        int e = ebase + hh * 16 + n16;
        rba[hh] = bap[e];
        rbi[hh] = bip[e];
        ral[hh] = sigf(gp[e]);
    }

    if (tid < 32) carry[tid] = 0.0f;

    const float* xrow = x + (size_t)b * SEQ * DIM;
    _Float16* cmbb = cmb + (size_t)b * SEQ * NCH + cg * 32;

    __syncthreads();

    for (int t = 0; t < 32; ++t) {
        const int s0 = t * 64;

        // ---- stage x tile fp32->fp16 (coalesced 32B/lane reads) ----
#pragma unroll
        for (int i = 0; i < 4; ++i) {
            int g = tid + i * 256;               // 1024 granules of 8 floats
            int r = g >> 4, d8 = g & 15;
            const float* srcx = xrow + (size_t)(s0 + r) * DIM + d8 * 8;
            float4 v0 = *(const float4*)srcx;
            float4 v1 = *(const float4*)(srcx + 4);
            half8 hv;
            hv[0] = (_Float16)v0.x; hv[1] = (_Float16)v0.y;
            hv[2] = (_Float16)v0.z; hv[3] = (_Float16)v0.w;
            hv[4] = (_Float16)v1.x; hv[5] = (_Float16)v1.y;
            hv[6] = (_Float16)v1.z; hv[7] = (_Float16)v1.w;
            *(half8*)&xs[r][d8 * 8] = hv;
        }
        __syncthreads();

        // ---- MFMA: C[s = w*16 + quad*4+reg][j], 4 n-tiles, K=128 ----
        f32x4 acc[4];
#pragma unroll
        for (int nt = 0; nt < 4; ++nt) acc[nt] = (f32x4){0.f, 0.f, 0.f, 0.f};
#pragma unroll
        for (int ks = 0; ks < 4; ++ks) {
            half8 af = *(const half8*)&xs[w * 16 + n16][ks * 32 + quad * 8];
#pragma unroll
            for (int nt = 0; nt < 4; ++nt)
                acc[nt] = __builtin_amdgcn_mfma_f32_16x16x32_f16(af, bf[ks][nt], acc[nt], 0, 0, 0);
        }

        // ---- gates + 4-step affine compose (s = s0 + w*16 + quad*4 + reg) ----
        const int sbase = s0 + w * 16 + quad * 4;
        float a_s[2][4], u_s[2][4];
#pragma unroll
        for (int hh = 0; hh < 2; ++hh) {
            float A4 = 1.0f, U4 = 0.0f;
#pragma unroll
            for (int reg = 0; reg < 4; ++reg) {
                float sc = p ? __expf((float)(sbase + reg) * (3.0f / 2047.0f)) : 1.0f;
                float pa = fmaf(acc[hh][reg],     sc, rba[hh]);
                float pi = fmaf(acc[2 + hh][reg], sc, rbi[hh]);
                float rst = sigf(pa);
                float ig  = sigf(pi);
                float a   = ral[hh] * exp2f(-rst * 1.5849625007211562f);  // alpha*3^-rst
                float u   = sqrtf(fmaxf(1.0f - a * a, 0.0f)) * ig * pi;
                a_s[hh][reg] = a; u_s[hh][reg] = u;
                A4 *= a;
                U4 = fmaf(a, U4, u);
            }
            seg[w * 4 + quad][hh * 16 + n16] = make_float2(A4, U4);
        }
        __syncthreads();

        // ---- serial inter-segment scan (16 segments, lane = channel) ----
        if (tid < 32) {
            float H = carry[tid];
#pragma unroll
            for (int ts = 0; ts < 16; ++ts) {
                float2 AU = seg[ts][tid];
                pref[ts][tid] = H;
                H = fmaf(AU.x, H, AU.y);
            }
            carry[tid] = H;
        }
        __syncthreads();

        // ---- replay with incoming h -> hbuf ----
#pragma unroll
        for (int hh = 0; hh < 2; ++hh) {
            float h = pref[w * 4 + quad][hh * 16 + n16];
#pragma unroll
            for (int reg = 0; reg < 4; ++reg) {
                h = fmaf(a_s[hh][reg], h, u_s[hh][reg]);
                hbuf[w * 16 + quad * 4 + reg][hh * 16 + n16] = (_Float16)h;
            }
        }
        __syncthreads();

        // ---- coalesced cmb store: 64 rows x 32 halfs ----
        {
            int row = tid >> 2, part = tid & 3;
            half8 hv = *(const half8*)&hbuf[row][part * 8];
            *(half8*)(cmbb + (size_t)(s0 + row) * NCH + part * 8) = hv;
        }
        // xs rewrite next tile is ordered by the stage barrier; hbuf reads are
        // drained by the compiler's waitcnt before that barrier.
    }
}

// ---------------------------------------------------------------------------
// k3: out[65536,128] = cmb(fp16) @ Wf^T(fp16) + bf  via mfma_f32_16x16x32_f16.
//     (unchanged from round 3 — verified)
// ---------------------------------------------------------------------------
__global__ __launch_bounds__(256, 2) void k3_mfma(
        const _Float16* __restrict__ cmb, const _Float16* __restrict__ Wfg,
        const float* __restrict__ bfv, float* __restrict__ out) {
    __shared__ _Float16 As[16 * 512];
    __shared__ _Float16 Bs[16 * 512];

    const int tid  = threadIdx.x;
    const int lane = tid & 63;
    const int w    = tid >> 6;
    const int row0 = blockIdx.x * 128;
    const int q    = lane >> 4;
    const int nn   = lane & 15;

    f32x4 acc[2][8];
#pragma unroll
    for (int rt = 0; rt < 2; ++rt)
#pragma unroll
        for (int ct = 0; ct < 8; ++ct)
            acc[rt][ct] = (f32x4){0.0f, 0.0f, 0.0f, 0.0f};

    for (int kb = 0; kb < 8; ++kb) {
        const int kc = kb * 64;
#pragma unroll
        for (int i = 0; i < 4; ++i) {
            int f = tid + i * 256;
            int r = f >> 3, k8 = f & 7;
            uint4 v = *(const uint4*)(cmb + (size_t)(row0 + r) * NCH + kc + k8 * 8);
            int rt = r >> 4, m = r & 15, ks = k8 >> 2, qq = k8 & 3;
            *(uint4*)&As[(((rt * 2 + ks) * 64) + qq * 16 + m) * 8] = v;
        }
#pragma unroll
        for (int i = 0; i < 4; ++i) {
            int f = tid + i * 256;
            uint4 v = *(const uint4*)(Wfg + (size_t)kb * 8192 + (size_t)f * 8);
            *(uint4*)&Bs[(size_t)f * 8] = v;
        }
        __syncthreads();

#pragma unroll
        for (int ks = 0; ks < 2; ++ks) {
            half8 a0 = *(const half8*)&As[(((w * 2 + 0) * 2 + ks) * 512) + lane * 8];
            half8 a1 = *(const half8*)&As[(((w * 2 + 1) * 2 + ks) * 512) + lane * 8];
#pragma unroll
            for (int ct = 0; ct < 8; ++ct) {
                half8 bb = *(const half8*)&Bs[((ks * 8 + ct) * 512) + lane * 8];
                acc[0][ct] = __builtin_amdgcn_mfma_f32_16x16x32_f16(a0, bb, acc[0][ct], 0, 0, 0);
                acc[1][ct] = __builtin_amdgcn_mfma_f32_16x16x32_f16(a1, bb, acc[1][ct], 0, 0, 0);
            }
        }
        __syncthreads();
    }

#pragma unroll
    for (int rt = 0; rt < 2; ++rt) {
        int rbase = row0 + w * 32 + rt * 16 + q * 4;
#pragma unroll
        for (int ct = 0; ct < 8; ++ct) {
            int col = ct * 16 + nn;
            float bias = bfv[col];
#pragma unroll
            for (int reg = 0; reg < 4; ++reg)
                out[(size_t)(rbase + reg) * DIM + col] = acc[rt][ct][reg] + bias;
        }
    }
}

// ---------------------------------------------------------------------------
extern "C" void kernel_launch(void* const* d_in, const int* in_sizes, int n_in,
                              void* d_out, int out_size, void* d_ws, size_t ws_size,
                              hipStream_t stream) {
    if (ws_size < WS_NEEDED) return;

    const float* x    = (const float*)d_in[0];
    const float* Wa_u = (const float*)d_in[1];
    const float* ba_u = (const float*)d_in[2];
    const float* Wi_u = (const float*)d_in[3];
    const float* bi_u = (const float*)d_in[4];
    const float* g_u  = (const float*)d_in[5];
    const float* Wa_w = (const float*)d_in[6];
    const float* ba_w = (const float*)d_in[7];
    const float* Wi_w = (const float*)d_in[8];
    const float* bi_w = (const float*)d_in[9];
    const float* g_w  = (const float*)d_in[10];
    const float* Wf   = (const float*)d_in[11];
    const float* bfv  = (const float*)d_in[12];
    float* out = (float*)d_out;

    char* ws = (char*)d_ws;
    _Float16* cmb = (_Float16*)ws;
    _Float16* Wfg = (_Float16*)(ws + WFG_OFF);

    hipLaunchKernelGGL(k0_wfg, dim3(256), dim3(256), 0, stream, Wf, Wfg);
    hipLaunchKernelGGL(kfused, dim3(32, 16), dim3(256), 0, stream,
                       x, Wa_u, ba_u, Wi_u, bi_u, g_u,
                       Wa_w, ba_w, Wi_w, bi_w, g_w, cmb);
    hipLaunchKernelGGL(k3_mfma, dim3(512), dim3(256), 0, stream,
                       cmb, Wfg, bfv, out);
}